// Round 2
// baseline (261.391 us; speedup 1.0000x reference)
//
#include <hip/hip_runtime.h>

#define DIM 192
#define PLANE (DIM * DIM)              // 36864
#define VOL ((size_t)PLANE * DIM)      // 7077888
#define NTOT (2.0 * 14155776.0 / 2.0)  // 14155776 voxels total; kept explicit below

__device__ __forceinline__ float robustf(float x) {
    float ax = fabsf(x);
    return (ax <= 0.01f) ? (0.5f * x * x) : (0.01f * (ax - 0.005f));
}

__device__ __forceinline__ float4 ldg4(const float* __restrict__ p) {
    return *(const float4*)p;
}

// per-voxel contribution from the 9 gradient components
__device__ __forceinline__ float voxel_loss(
    float du_dx, float du_dy, float du_dz,
    float dv_dx, float dv_dy, float dv_dz,
    float dw_dx, float dw_dy, float dw_dz) {
    const float E_xy = 0.5f * (du_dy + dv_dx);
    const float E_xz = 0.5f * (du_dz + dw_dx);
    const float E_yz = 0.5f * (dv_dz + dw_dy);
    const float tr   = du_dx + dv_dy + dw_dz;

    const float rtr = robustf(tr);
    const float rxx = robustf(du_dx), ryy = robustf(dv_dy), rzz = robustf(dw_dz);
    const float rxy = robustf(E_xy),  rxz = robustf(E_xz),  ryz = robustf(E_yz);

    const float energy = 0.5f * rtr * rtr
                       + 0.5f * (rxx * rxx + ryy * ryy + rzz * rzz
                                 + 2.0f * (rxy * rxy + rxz * rxz + ryz * ryz));

    // Replicate the reference expression EXACTLY (not the true determinant).
    const float jac =
          (1.0f + du_dx) * ((1.0f + dv_dy) * (1.0f + dw_dz) - dv_dz * dw_dy)
        - du_dy * (dv_dx * (1.0f + dw_dz) - dv_dz * (1.0f + dw_dx))
        + du_dz * (dv_dx * dw_dy - (1.0f + dv_dy) * (1.0f + dw_dx));

    return energy + 0.1f * fmaxf(-jac, 0.0f);
}

// z-gradient of a float4 row chunk; lf = element k4-1 (prev lane .w),
// rt = element k4+4 (next lane .x)
__device__ __forceinline__ float4 zgrad(float4 c, float lf, float rt,
                                        bool leftEdge, bool rightEdge) {
    float4 g;
    g.x = leftEdge  ? (c.y - c.x) : 0.5f * (c.y - lf);
    g.y = 0.5f * (c.z - c.x);
    g.z = 0.5f * (c.w - c.y);
    g.w = rightEdge ? (c.w - c.z) : 0.5f * (rt - c.z);
    return g;
}

__global__ __launch_bounds__(256)
void elastic_main(const float* __restrict__ df, double* __restrict__ acc) {
    const int tx = threadIdx.x;        // 0..63 = one wave per j-row; lanes 0..47 active
    const int ty = threadIdx.y;        // 0..3  -> j row within block
    const int k4 = tx * 4;             // k = k4..k4+3 (float4, 16B-aligned)
    const int j  = blockIdx.x * 4 + ty;
    const int i0 = blockIdx.y * 16;
    const int b  = blockIdx.z;

    const float* __restrict__ u = df + (size_t)(b * 3 + 0) * VOL;
    const float* __restrict__ v = df + (size_t)(b * 3 + 1) * VOL;
    const float* __restrict__ w = df + (size_t)(b * 3 + 2) * VOL;

    const int jp = (j < DIM - 1) ? j + 1 : j;
    const int jm = (j > 0) ? j - 1 : j;
    const float sy = ((jp - jm) == 2) ? 0.5f : 1.0f;

    const bool act = (tx < 48);
    const bool leftEdge  = (tx == 0);
    const bool rightEdge = (tx == 47);

    float vsum = 0.0f;

    for (int ii = 0; ii < 16; ++ii) {
        const int i = i0 + ii;
        const int ip = (i < DIM - 1) ? i + 1 : i;
        const int im = (i > 0) ? i - 1 : i;
        const float sx = ((ip - im) == 2) ? 0.5f : 1.0f;

        const size_t oC  = (size_t)i  * PLANE + (size_t)j  * DIM + k4;
        const size_t oXp = (size_t)ip * PLANE + (size_t)j  * DIM + k4;
        const size_t oXm = (size_t)im * PLANE + (size_t)j  * DIM + k4;
        const size_t oYp = (size_t)i  * PLANE + (size_t)jp * DIM + k4;
        const size_t oYm = (size_t)i  * PLANE + (size_t)jm * DIM + k4;

        float4 uc, vc, wc;
        float4 uxp, uxm, vxp, vxm, wxp, wxm;
        float4 uyp, uym, vyp, vym, wyp, wym;

        if (act) {
            uc  = ldg4(u + oC);  vc  = ldg4(v + oC);  wc  = ldg4(w + oC);
            uxp = ldg4(u + oXp); uxm = ldg4(u + oXm);
            vxp = ldg4(v + oXp); vxm = ldg4(v + oXm);
            wxp = ldg4(w + oXp); wxm = ldg4(w + oXm);
            uyp = ldg4(u + oYp); uym = ldg4(u + oYm);
            vyp = ldg4(v + oYp); vym = ldg4(v + oYm);
            wyp = ldg4(w + oYp); wym = ldg4(w + oYm);
        } else {
            // keep shuffle-source registers defined for idle lanes
            uc = vc = wc = make_float4(0.f, 0.f, 0.f, 0.f);
        }

        // k-neighbor exchange (row edges never need cross-lane values)
        const float ulf = __shfl_up(uc.w, 1);
        const float vlf = __shfl_up(vc.w, 1);
        const float wlf = __shfl_up(wc.w, 1);
        const float urt = __shfl_down(uc.x, 1);
        const float vrt = __shfl_down(vc.x, 1);
        const float wrt = __shfl_down(wc.x, 1);

        if (act) {
            const float4 du_dz = zgrad(uc, ulf, urt, leftEdge, rightEdge);
            const float4 dv_dz = zgrad(vc, vlf, vrt, leftEdge, rightEdge);
            const float4 dw_dz = zgrad(wc, wlf, wrt, leftEdge, rightEdge);

            float4 du_dx, dv_dx, dw_dx, du_dy, dv_dy, dw_dy;
            du_dx.x = (uxp.x - uxm.x) * sx; du_dx.y = (uxp.y - uxm.y) * sx;
            du_dx.z = (uxp.z - uxm.z) * sx; du_dx.w = (uxp.w - uxm.w) * sx;
            dv_dx.x = (vxp.x - vxm.x) * sx; dv_dx.y = (vxp.y - vxm.y) * sx;
            dv_dx.z = (vxp.z - vxm.z) * sx; dv_dx.w = (vxp.w - vxm.w) * sx;
            dw_dx.x = (wxp.x - wxm.x) * sx; dw_dx.y = (wxp.y - wxm.y) * sx;
            dw_dx.z = (wxp.z - wxm.z) * sx; dw_dx.w = (wxp.w - wxm.w) * sx;
            du_dy.x = (uyp.x - uym.x) * sy; du_dy.y = (uyp.y - uym.y) * sy;
            du_dy.z = (uyp.z - uym.z) * sy; du_dy.w = (uyp.w - uym.w) * sy;
            dv_dy.x = (vyp.x - vym.x) * sy; dv_dy.y = (vyp.y - vym.y) * sy;
            dv_dy.z = (vyp.z - vym.z) * sy; dv_dy.w = (vyp.w - vym.w) * sy;
            dw_dy.x = (wyp.x - wym.x) * sy; dw_dy.y = (wyp.y - wym.y) * sy;
            dw_dy.z = (wyp.z - wym.z) * sy; dw_dy.w = (wyp.w - wym.w) * sy;

            vsum += voxel_loss(du_dx.x, du_dy.x, du_dz.x,
                               dv_dx.x, dv_dy.x, dv_dz.x,
                               dw_dx.x, dw_dy.x, dw_dz.x);
            vsum += voxel_loss(du_dx.y, du_dy.y, du_dz.y,
                               dv_dx.y, dv_dy.y, dv_dz.y,
                               dw_dx.y, dw_dy.y, dw_dz.y);
            vsum += voxel_loss(du_dx.z, du_dy.z, du_dz.z,
                               dv_dx.z, dv_dy.z, dv_dz.z,
                               dw_dx.z, dw_dy.z, dw_dz.z);
            vsum += voxel_loss(du_dx.w, du_dy.w, du_dz.w,
                               dv_dx.w, dv_dy.w, dv_dz.w,
                               dw_dx.w, dw_dy.w, dw_dz.w);
        }
    }

    // wave-64 reduction (idle lanes carry 0)
    #pragma unroll
    for (int off = 32; off > 0; off >>= 1)
        vsum += __shfl_down(vsum, off, 64);

    __shared__ float wpart[4];
    if (tx == 0) wpart[ty] = vsum;
    __syncthreads();
    if (tx == 0 && ty == 0) {
        double s = (double)wpart[0] + (double)wpart[1]
                 + (double)wpart[2] + (double)wpart[3];
        unsafeAtomicAdd(acc, s);   // 1152 hw f64 atomics total — no contention
    }
}

__global__ void elastic_finalize(const double* __restrict__ acc, float* __restrict__ out) {
    out[0] = (float)(acc[0] * (1.0 / 14155776.0));
}

extern "C" void kernel_launch(void* const* d_in, const int* in_sizes, int n_in,
                              void* d_out, int out_size, void* d_ws, size_t ws_size,
                              hipStream_t stream) {
    const float* df = (const float*)d_in[0];
    double* acc = (double*)d_ws;
    float* out = (float*)d_out;

    hipMemsetAsync(d_ws, 0, sizeof(double), stream);

    dim3 grid(48, 12, 2);      // 48 j-tiles, 12 i-chunks of 16, 2 batches
    dim3 block(64, 4);         // wave per j-row; lanes 0..47 active (float4 over k)
    elastic_main<<<grid, block, 0, stream>>>(df, acc);
    elastic_finalize<<<1, 1, 0, stream>>>(acc, out);
}

// Round 3
// 254.450 us; speedup vs baseline: 1.0273x; 1.0273x over previous
//
#include <hip/hip_runtime.h>

#define DIM 192
#define PLANE (DIM * DIM)              // 36864
#define VOL ((size_t)PLANE * DIM)      // 7077888

__device__ __forceinline__ float robustf(float x) {
    float ax = fabsf(x);
    return (ax <= 0.01f) ? (0.5f * x * x) : (0.01f * (ax - 0.005f));
}

__device__ __forceinline__ float4 ldg4(const float* __restrict__ p) {
    return *(const float4*)p;
}

__device__ __forceinline__ float4 sub_scale(float4 a, float4 b, float s) {
    return make_float4((a.x - b.x) * s, (a.y - b.y) * s,
                       (a.z - b.z) * s, (a.w - b.w) * s);
}

__device__ __forceinline__ float voxel_loss(
    float du_dx, float du_dy, float du_dz,
    float dv_dx, float dv_dy, float dv_dz,
    float dw_dx, float dw_dy, float dw_dz) {
    const float E_xy = 0.5f * (du_dy + dv_dx);
    const float E_xz = 0.5f * (du_dz + dw_dx);
    const float E_yz = 0.5f * (dv_dz + dw_dy);
    const float tr   = du_dx + dv_dy + dw_dz;

    const float rtr = robustf(tr);
    const float rxx = robustf(du_dx), ryy = robustf(dv_dy), rzz = robustf(dw_dz);
    const float rxy = robustf(E_xy),  rxz = robustf(E_xz),  ryz = robustf(E_yz);

    const float energy = 0.5f * rtr * rtr
                       + 0.5f * (rxx * rxx + ryy * ryy + rzz * rzz
                                 + 2.0f * (rxy * rxy + rxz * rxz + ryz * ryz));

    // Replicate the reference expression EXACTLY (not the true determinant).
    const float jac =
          (1.0f + du_dx) * ((1.0f + dv_dy) * (1.0f + dw_dz) - dv_dz * dw_dy)
        - du_dy * (dv_dx * (1.0f + dw_dz) - dv_dz * (1.0f + dw_dx))
        + du_dz * (dv_dx * dw_dy - (1.0f + dv_dy) * (1.0f + dw_dx));

    return energy + 0.1f * fmaxf(-jac, 0.0f);
}

__device__ __forceinline__ float4 zgrad(float4 c, float lf, float rt,
                                        bool leftEdge, bool rightEdge) {
    float4 g;
    g.x = leftEdge  ? (c.y - c.x) : 0.5f * (c.y - lf);
    g.y = 0.5f * (c.z - c.x);
    g.z = 0.5f * (c.w - c.y);
    g.w = rightEdge ? (c.w - c.z) : 0.5f * (rt - c.z);
    return g;
}

// i-march with register rotation: center rows of planes i-1, i, i+1 live in
// registers (9 float4), so each x-plane is loaded exactly once per block.
__global__ __launch_bounds__(256, 4)
void elastic_main(const float* __restrict__ df, double* __restrict__ acc) {
    const int tx = threadIdx.x;        // 0..63, one wave per j-row; lanes 0..47 active
    const int ty = threadIdx.y;        // 0..3 -> j row within block
    const int k4 = tx * 4;
    const int j  = blockIdx.x * 4 + ty;
    const int i0 = blockIdx.y * 24;
    const int b  = blockIdx.z;

    const float* __restrict__ u = df + (size_t)(b * 3 + 0) * VOL;
    const float* __restrict__ v = df + (size_t)(b * 3 + 1) * VOL;
    const float* __restrict__ w = df + (size_t)(b * 3 + 2) * VOL;

    const int jp = (j < DIM - 1) ? j + 1 : j;
    const int jm = (j > 0) ? j - 1 : j;
    const float sy = ((jp - jm) == 2) ? 0.5f : 1.0f;

    const bool act = (tx < 48);
    const bool leftEdge  = (tx == 0);
    const bool rightEdge = (tx == 47);

    // rotation registers: planes max(i-1,0), i, min(i+1,191) center rows
    float4 um, vm, wm, uc, vc, wc;
    um = vm = wm = uc = vc = wc = make_float4(0.f, 0.f, 0.f, 0.f);

    {
        const int im1 = (i0 > 0) ? i0 - 1 : 0;
        const size_t oM = (size_t)im1 * PLANE + (size_t)j * DIM + k4;
        const size_t oC = (size_t)i0  * PLANE + (size_t)j * DIM + k4;
        if (act) {
            um = ldg4(u + oM); vm = ldg4(v + oM); wm = ldg4(w + oM);
            uc = ldg4(u + oC); vc = ldg4(v + oC); wc = ldg4(w + oC);
        }
    }

    float vsum = 0.0f;

    for (int ii = 0; ii < 24; ++ii) {
        const int i   = i0 + ii;
        const int ip1 = (i < DIM - 1) ? i + 1 : i;
        const int im1 = (i > 0) ? i - 1 : i;
        const float sx = ((ip1 - im1) == 2) ? 0.5f : 1.0f;

        const size_t oP  = (size_t)ip1 * PLANE + (size_t)j  * DIM + k4;
        const size_t oYp = (size_t)i   * PLANE + (size_t)jp * DIM + k4;
        const size_t oYm = (size_t)i   * PLANE + (size_t)jm * DIM + k4;

        float4 up, vp, wp, uyp, uym, vyp, vym, wyp, wym;
        up = vp = wp = make_float4(0.f, 0.f, 0.f, 0.f);
        if (act) {
            up  = ldg4(u + oP);  vp  = ldg4(v + oP);  wp  = ldg4(w + oP);
            uyp = ldg4(u + oYp); uym = ldg4(u + oYm);
            vyp = ldg4(v + oYp); vym = ldg4(v + oYm);
            wyp = ldg4(w + oYp); wym = ldg4(w + oYm);
        }

        // z-neighbor exchange from center-plane rotation registers
        const float ulf = __shfl_up(uc.w, 1);
        const float vlf = __shfl_up(vc.w, 1);
        const float wlf = __shfl_up(wc.w, 1);
        const float urt = __shfl_down(uc.x, 1);
        const float vrt = __shfl_down(vc.x, 1);
        const float wrt = __shfl_down(wc.x, 1);

        if (act) {
            const float4 du_dz = zgrad(uc, ulf, urt, leftEdge, rightEdge);
            const float4 dv_dz = zgrad(vc, vlf, vrt, leftEdge, rightEdge);
            const float4 dw_dz = zgrad(wc, wlf, wrt, leftEdge, rightEdge);

            const float4 du_dx = sub_scale(up, um, sx);
            const float4 dv_dx = sub_scale(vp, vm, sx);
            const float4 dw_dx = sub_scale(wp, wm, sx);
            const float4 du_dy = sub_scale(uyp, uym, sy);
            const float4 dv_dy = sub_scale(vyp, vym, sy);
            const float4 dw_dy = sub_scale(wyp, wym, sy);

            vsum += voxel_loss(du_dx.x, du_dy.x, du_dz.x,
                               dv_dx.x, dv_dy.x, dv_dz.x,
                               dw_dx.x, dw_dy.x, dw_dz.x);
            vsum += voxel_loss(du_dx.y, du_dy.y, du_dz.y,
                               dv_dx.y, dv_dy.y, dv_dz.y,
                               dw_dx.y, dw_dy.y, dw_dz.y);
            vsum += voxel_loss(du_dx.z, du_dy.z, du_dz.z,
                               dv_dx.z, dv_dy.z, dv_dz.z,
                               dw_dx.z, dw_dy.z, dw_dz.z);
            vsum += voxel_loss(du_dx.w, du_dy.w, du_dz.w,
                               dv_dx.w, dv_dy.w, dv_dz.w,
                               dw_dx.w, dw_dy.w, dw_dz.w);
        }

        // rotate planes: i-1 <- i, i <- i+1
        um = uc; vm = vc; wm = wc;
        uc = up; vc = vp; wc = wp;
    }

    #pragma unroll
    for (int off = 32; off > 0; off >>= 1)
        vsum += __shfl_down(vsum, off, 64);

    __shared__ float wpart[4];
    if (tx == 0) wpart[ty] = vsum;
    __syncthreads();
    if (tx == 0 && ty == 0) {
        double s = (double)wpart[0] + (double)wpart[1]
                 + (double)wpart[2] + (double)wpart[3];
        unsafeAtomicAdd(acc, s);   // 768 hw f64 atomics total
    }
}

__global__ void elastic_finalize(const double* __restrict__ acc, float* __restrict__ out) {
    out[0] = (float)(acc[0] * (1.0 / 14155776.0));
}

extern "C" void kernel_launch(void* const* d_in, const int* in_sizes, int n_in,
                              void* d_out, int out_size, void* d_ws, size_t ws_size,
                              hipStream_t stream) {
    const float* df = (const float*)d_in[0];
    double* acc = (double*)d_ws;
    float* out = (float*)d_out;

    hipMemsetAsync(d_ws, 0, sizeof(double), stream);

    dim3 grid(48, 8, 2);       // 48 j-tiles, 8 i-chunks of 24, 2 batches = 768 blocks (3/CU)
    dim3 block(64, 4);
    elastic_main<<<grid, block, 0, stream>>>(df, acc);
    elastic_finalize<<<1, 1, 0, stream>>>(acc, out);
}